// Round 1
// baseline (219.791 us; speedup 1.0000x reference)
//
#include <hip/hip_runtime.h>

// MXFP (e2m1, group=32) quantize-dequantize of f32 tensor [4,32,2048,128].
// Groups of 32 are contiguous along the last dim. All arithmetic is exact
// power-of-two scaling + RNE mantissa rounding, so we replicate the
// reference bit-exactly with pure bit ops (no transcendentals):
//   scale_exp = ilogb(group_max) - 2            (== floor(log2(max)) - 2 for
//                                                 x_max in (2^-8, 2^8); see
//                                                 session notes on log2
//                                                 rounding windows)
//   xd = x * 2^-scale_exp
//   |xd| <= 0.25 -> 0
//   else e2m1 RNE quantize: q = rndne(2*mant(|xd|)) in {2,3,4};
//        x_rnd = q * 2^(ilogb(|xd|)-1); clamp [0.5, 6]; restore sign
//   out = r * 2^scale_exp

__global__ __launch_bounds__(256) void
mxfp_quant_kernel(const float* __restrict__ x, float* __restrict__ out, int n4) {
    int i = blockIdx.x * 256 + threadIdx.x;
    if (i >= n4) return;

    const float4* __restrict__ x4 = (const float4*)x;
    float4* __restrict__ o4 = (float4*)out;

    float4 v = x4[i];

    // thread-local absmax over 4 elements
    float amax = fmaxf(fmaxf(fabsf(v.x), fabsf(v.y)),
                       fmaxf(fabsf(v.z), fabsf(v.w)));
    // 8 consecutive lanes hold one group of 32; butterfly max over them
    amax = fmaxf(amax, __shfl_xor(amax, 1, 64));
    amax = fmaxf(amax, __shfl_xor(amax, 2, 64));
    amax = fmaxf(amax, __shfl_xor(amax, 4, 64));

    if (amax == 0.0f) amax = 1.0f;  // reference: where(max==0, 1, max)

    // exact floor(log2(amax)) for normal amax
    int e = (int)(__float_as_uint(amax) >> 23) - 127;
    int se = e - 2;
    // keep scale/inv_scale normal; only deviates from ref for x_max
    // outside (2^-124, 2^129) which cannot occur for this input
    se = se < -126 ? -126 : (se > 127 ? 127 : se);
    float scale     = __uint_as_float((unsigned)(se + 127) << 23);  // 2^se
    float inv_scale = __uint_as_float((unsigned)(127 - se) << 23);  // 2^-se

    float4 o;
    float* vp = &v.x;
    float* op = &o.x;
#pragma unroll
    for (int c = 0; c < 4; ++c) {
        float xd = vp[c] * inv_scale;   // exact: power-of-two multiply
        float ax = fabsf(xd);
        // e2m1 quantization of ax (only valid/used when ax > 0.25)
        unsigned b = __float_as_uint(ax);
        int e2 = (int)(b >> 23) - 127;                      // floor(log2 ax)
        float m = __uint_as_float((b & 0x007FFFFFu) | 0x3F800000u);  // [1,2)
        float q = rintf(m * 2.0f);                          // {2,3,4}, RNE
        // q * 2^(e2-1); e2 in [-2,2] whenever ax > 0.25 (|xd| < 8 by constr.)
        float x_rnd = q * __uint_as_float((unsigned)(e2 + 126) << 23);
        float xc = fminf(fmaxf(x_rnd, 0.5f), 6.0f);
        float r = copysignf(xc, xd);
        r = (ax <= 0.25f) ? 0.0f : r;   // flush-to-zero (also covers xd==0)
        op[c] = r * scale;              // exact: power-of-two multiply
    }

    o4[i] = o;
}

extern "C" void kernel_launch(void* const* d_in, const int* in_sizes, int n_in,
                              void* d_out, int out_size, void* d_ws, size_t ws_size,
                              hipStream_t stream) {
    const float* x = (const float*)d_in[0];
    float* out = (float*)d_out;
    int n = in_sizes[0];        // 33,554,432 (divisible by 128)
    int n4 = n / 4;             // one float4 per thread; 8 threads per group
    int block = 256;
    int grid = (n4 + block - 1) / block;
    mxfp_quant_kernel<<<grid, block, 0, stream>>>(x, out, n4);
}